// Round 6
// baseline (287.859 us; speedup 1.0000x reference)
//
#include <hip/hip_runtime.h>
#include <hip/hip_bf16.h>

// SeqAttention: banded relative-position attention.
// out[b,i,:] = softmax_k( (q_i . key[i+k] + q_i . pe[:,k]) / 8 ) @ value[i+k,:], k in [0,1024)
//
// R13: T15 double-pipeline. Evidence R8-R12: barriers/LDS-traffic/occupancy
// changes are all neutral; VMEM-direct K/V is latency-fatal; VALU cycles
// invariant ~50%. Remaining lever: overlap softmax(t-1) [VALU+shuffle] with
// QK/PE MFMAs of tile t inside each wave (T15, +7-11% on attn per catalog).
//  - per iteration: stage(t); QK(t)+PE(t) MFMAs; softmax(t-1); bar3;
//    P(t-1)->sK; PV(t-1) from double-buffered sV.
//  - cur packed to bf16 pairs right after PE MFMAs (8 u32 carried, not 16
//    f32); prevw3 recovered from packed words (same rounding class).
//  - PE fragments global-direct from peT (128KB, shared by all blocks ->
//    L1/L2-pinned; hides under QK ds_reads). Drops sPE (-16KB) + pfP regs.
//  - K/V keep reg-prefetch staging (R12 lesson: bulk operands need LDS).
//  - 9x2 manually-unrolled phases: buffer parity + reg-set compile-time.
// LDS 24KB; spill tripwire = WRITE_SIZE (must stay 16384).

typedef __attribute__((ext_vector_type(8))) short bf16x8;
typedef __attribute__((ext_vector_type(4))) short bf16x4;
typedef __attribute__((ext_vector_type(4))) float f32x4;

#define BHN   64
#define MQ    1024
#define DH    64
#define LS    1024
#define NKEY  2048
#define NTILE 17

#define SZ_PE  ((size_t)LS * DH * 2)              // 131072, swizzled bf16 [rel][d]
#define OFF_K  SZ_PE
#define SZ_K   ((size_t)BHN * NKEY * DH * 2)      // bf16, rows pre-swizzled
#define OFF_V  (OFF_K + SZ_K)
#define SZ_V   ((size_t)BHN * DH * NKEY * 2)      // bf16 V^T [bh][d][kappa-key]
#define WS_NEED (OFF_V + SZ_V)                    // ~33.7 MB

// 0.125 (1/sqrt(64)) * log2(e): folded into Q before bf16 cast
#define SCL_LOG2E 0.18033688011112042f

__device__ __forceinline__ short f2bf(float f) {
  unsigned u = __float_as_uint(f);
  u += 0x7FFFu + ((u >> 16) & 1u);                // RNE (inputs finite)
  return (short)(u >> 16);
}
__device__ __forceinline__ float bf2f(short s) {
  return __uint_as_float(((unsigned)(unsigned short)s) << 16);
}

#if defined(__has_builtin)
#if __has_builtin(__builtin_amdgcn_cvt_pk_bf16_f32)
#define HAVE_CVT_PK 1
#endif
#if __has_builtin(__builtin_amdgcn_exp2f)
#define HAVE_EXP2 1
#endif
#endif

__device__ __forceinline__ float fast_exp2(float x) {
#ifdef HAVE_EXP2
  return __builtin_amdgcn_exp2f(x);               // raw v_exp_f32 (args bounded)
#else
  return __builtin_exp2f(x);
#endif
}

// pack two f32 -> two bf16 (RNE) in one unsigned
__device__ __forceinline__ unsigned pk2(float a, float b) {
#ifdef HAVE_CVT_PK
  auto r = __builtin_amdgcn_cvt_pk_bf16_f32(a, b);
  unsigned u;
  __builtin_memcpy(&u, &r, 4);
  return u;
#else
  return (unsigned)(unsigned short)f2bf(a) | ((unsigned)(unsigned short)f2bf(b) << 16);
#endif
}
__device__ __forceinline__ bf16x4 mk4(unsigned a, unsigned b) {
  union { unsigned u[2]; bf16x4 v; } z;
  z.u[0] = a; z.u[1] = b;
  return z.v;
}
__device__ __forceinline__ bf16x8 mk8(unsigned a, unsigned b, unsigned c, unsigned d) {
  union { unsigned u[4]; bf16x8 v; } z;
  z.u[0] = a; z.u[1] = b; z.u[2] = c; z.u[3] = d;
  return z.v;
}

// raw barrier: LDS-visibility only; in-flight global prefetch keeps flying
#define RAWBAR()                                          \
  do {                                                    \
    asm volatile("s_waitcnt lgkmcnt(0)" ::: "memory");    \
    __builtin_amdgcn_sched_barrier(0);                    \
    __builtin_amdgcn_s_barrier();                         \
    __builtin_amdgcn_sched_barrier(0);                    \
  } while (0)

// ---- fused prep: [0,256) PE, [256,2304) K, [2304,4352) V
// PE: [1,D,L] f32 -> peT [rel][d] bf16, granule-swizzled by (rel&7)
// K : [bh*2048][64] f32 -> bf16 rows, granule-swizzled by (row&7)
// V : [bh][2048][64] f32 -> bf16 V^T [bh][64][2048], key dim kappa-permuted
//     per 64-block: kappa = (k&15)*4 + (k>>4)  (inverse k = (kap&3)*16 + (kap>>2))
__global__ __launch_bounds__(256)
void prep_fused(const float* __restrict__ pe, const float* __restrict__ K,
                const float* __restrict__ V, short* __restrict__ peT,
                short* __restrict__ Kb, short* __restrict__ Vb) {
  __shared__ short st[64 * 68];
  const int bx = blockIdx.x;
  if (bx < 256) {
    const int idx = bx * 256 + threadIdx.x;       // 65536
    const int rel = idx >> 6, d = idx & 63;
    peT[rel * 64 + (((d >> 3) ^ (rel & 7)) * 8) + (d & 7)] = f2bf(pe[d * LS + rel]);
  } else if (bx < 2304) {
    const size_t i = ((size_t)(bx - 256) * 256 + threadIdx.x) * 16;  // < 8,388,608
    const int row = (int)(i >> 6);
    const int c16 = (int)(i & 63);                // 0,16,32,48
    const float4 f0 = *(const float4*)(K + i);
    const float4 f1 = *(const float4*)(K + i + 4);
    const float4 f2 = *(const float4*)(K + i + 8);
    const float4 f3 = *(const float4*)(K + i + 12);
    const bf16x8 b0 = mk8(pk2(f0.x, f0.y), pk2(f0.z, f0.w), pk2(f1.x, f1.y), pk2(f1.z, f1.w));
    const bf16x8 b1 = mk8(pk2(f2.x, f2.y), pk2(f2.z, f2.w), pk2(f3.x, f3.y), pk2(f3.z, f3.w));
    const int s7 = row & 7;
    short* dst = Kb + (size_t)row * 64;
    *(bf16x8*)&dst[(((c16 >> 3))     ^ s7) * 8] = b0;
    *(bf16x8*)&dst[(((c16 >> 3) + 1) ^ s7) * 8] = b1;
  } else {
    const int b  = bx - 2304;                     // 0..2047
    const int bh = b >> 5, jt = b & 31;
    {  // phase 1: stage 64x64 tile [key][d], f32->bf16
      const int r = threadIdx.x >> 2, cb = (threadIdx.x & 3) * 16;
      const float* src = V + ((size_t)bh * NKEY + jt * 64 + r) * DH + cb;
#pragma unroll
      for (int c = 0; c < 16; c += 8) {
        float4 f0 = *(const float4*)(src + c);
        float4 f1 = *(const float4*)(src + c + 4);
        *(bf16x8*)&st[r * 68 + cb + c] =
            mk8(pk2(f0.x, f0.y), pk2(f0.z, f0.w), pk2(f1.x, f1.y), pk2(f1.z, f1.w));
      }
    }
    __syncthreads();
    {  // phase 2: transpose + kappa-permute, contiguous b128 writes
      const int d = threadIdx.x >> 2, kapb = (threadIdx.x & 3) * 16;
      __attribute__((aligned(16))) short tmp[16];
#pragma unroll
      for (int j = 0; j < 16; ++j) {
        const int kap = kapb + j;
        const int k   = (kap & 3) * 16 + (kap >> 2);
        tmp[j] = st[k * 68 + d];
      }
      short* dst = Vb + ((size_t)bh * DH + d) * NKEY + jt * 64 + kapb;
      *(bf16x8*)dst       = *(bf16x8*)&tmp[0];
      *(bf16x8*)(dst + 8) = *(bf16x8*)&tmp[8];
    }
  }
}

// ---- S = Q @ K^T for one tile, from LDS sK (stored-XOR rows)
__device__ __forceinline__ void qk_tile(const short* sK, const bf16x8 (&aq)[2],
                                        int li, int quad, f32x4 (&cs)[4]) {
  const int g0 = ((quad) ^ (li & 7)) * 8;
  const int g1 = ((4 + quad) ^ (li & 7)) * 8;
#pragma unroll
  for (int nt = 0; nt < 4; ++nt) {
    const int row = (nt * 16 + li) * 64;
    f32x4 c = (f32x4){0.f, 0.f, 0.f, 0.f};
    c = __builtin_amdgcn_mfma_f32_16x16x32_bf16(aq[0], *(const bf16x8*)&sK[row + g0], c, 0, 0, 0);
    c = __builtin_amdgcn_mfma_f32_16x16x32_bf16(aq[1], *(const bf16x8*)&sK[row + g1], c, 0, 0, 0);
    cs[nt] = c;
  }
}

// ---- cur = Q @ PE, fragments DIRECT from peT (L1/L2-hot, 128KB shared),
// packed to bf16 pairs: pk[r*2] = (cur0,cur1)[r], pk[r*2+1] = (cur2,cur3)[r].
// colIdx clamped to [0,63]; clamped lanes are killed by the band masks.
__device__ __forceinline__ void pe_tile(const short* __restrict__ peT,
                                        const bf16x8 (&aq)[2], int t, int w,
                                        int li, int quad, unsigned (&pk)[8]) {
  const int g0 = ((quad) ^ (li & 7)) * 8;
  const int g1 = ((4 + quad) ^ (li & 7)) * 8;
  f32x4 cur[4];
#pragma unroll
  for (int m = 0; m < 4; ++m) {
    int cidx = 4 * t - w + m;
    cidx = cidx < 0 ? 0 : (cidx > 63 ? 63 : cidx);
    const short* p = peT + (size_t)(cidx * 16 + li) * 64;   // rel = cidx*16+li; rel&7 == li&7
    f32x4 c = (f32x4){0.f, 0.f, 0.f, 0.f};
    c = __builtin_amdgcn_mfma_f32_16x16x32_bf16(aq[0], *(const bf16x8*)(p + g0), c, 0, 0, 0);
    c = __builtin_amdgcn_mfma_f32_16x16x32_bf16(aq[1], *(const bf16x8*)(p + g1), c, 0, 0, 0);
    cur[m] = c;
  }
#pragma unroll
  for (int r = 0; r < 4; ++r) {
    pk[r * 2]     = pk2(cur[0][r], cur[1][r]);
    pk[r * 2 + 1] = pk2(cur[2][r], cur[3][r]);
  }
}

// ---- banded softmax for tile tt (register phase; no LDS except bpermute)
__device__ __forceinline__ void softmax_tile(const f32x4 (&cs)[4], const unsigned (&pk)[8],
                                             f32x4& prevw3, float (&l_i)[4],
                                             bf16x4 (&pkv)[4], int tt, int w,
                                             int li, int quad) {
#pragma unroll
  for (int r = 0; r < 4; ++r) {
    const int e       = li - quad * 4 - r;          // in [-15, 15]
    const bool ge     = (e >= 0);
    const int srcLane = quad * 16 + (e & 15);
    const float shm = __shfl(prevw3[r], srcLane);
    const unsigned s01 = (unsigned)__shfl((int)pk[r * 2], srcLane);
    const unsigned s23 = (unsigned)__shfl((int)pk[r * 2 + 1], srcLane);
    const float sh0 = bf2f((short)(s01 & 0xffffu));
    const float sh1 = bf2f((short)(s01 >> 16));
    const float sh2 = bf2f((short)(s23 & 0xffffu));
    const float sh3 = bf2f((short)(s23 >> 16));
    const float pos0 = ge ? sh0 : shm;
    const float pos1 = ge ? sh1 : sh0;
    const float pos2 = ge ? sh2 : sh1;
    const float pos3 = ge ? sh3 : sh2;
    float p0 = fast_exp2(cs[0][r] + pos0);
    float p1 = fast_exp2(cs[1][r] + pos1);
    float p2 = fast_exp2(cs[2][r] + pos2);
    float p3 = fast_exp2(cs[3][r] + pos3);
    if (tt == 0) {                 // valid iff dl>=0: nt>w || (nt==w && ge)
      p0 = (0 > w || (0 == w && ge)) ? p0 : 0.f;
      p1 = (1 > w || (1 == w && ge)) ? p1 : 0.f;
      p2 = (2 > w || (2 == w && ge)) ? p2 : 0.f;
      p3 = (3 > w || (3 == w && ge)) ? p3 : 0.f;
    } else if (tt == NTILE - 1) {  // valid iff dl<0: nt<w || (nt==w && !ge)
      p0 = (0 < w || (0 == w && !ge)) ? p0 : 0.f;
      p1 = (1 < w || (1 == w && !ge)) ? p1 : 0.f;
      p2 = (2 < w || (2 == w && !ge)) ? p2 : 0.f;
      p3 = (3 < w || (3 == w && !ge)) ? p3 : 0.f;
    }
    l_i[r] += (p0 + p1) + (p2 + p3);
    pkv[r] = mk4(pk2(p0, p1), pk2(p2, p3));
  }
  // prevw3 <- cur[3] of this tile, recovered from the packed words
#pragma unroll
  for (int r = 0; r < 4; ++r) prevw3[r] = bf2f((short)(pk[r * 2 + 1] >> 16));
}

// ---- P store (wave-private stripe of sP) + O += P @ V from sV slot
__device__ __forceinline__ void pv_tile(short* sP, const short* sV,
                                        const bf16x4 (&pkv)[4], f32x4 (&acco)[4],
                                        int w, int li, int quad) {
  const int rbase = w * 16 + quad * 4;
#pragma unroll
  for (int r = 0; r < 4; ++r) {
    const int rowA = rbase + r;
    *(bf16x4*)&sP[rowA * 64 + (((li >> 1) ^ (rowA & 7)) * 8) + (li & 1) * 4] = pkv[r];
  }
  const int rowA = w * 16 + li;
  __builtin_amdgcn_s_setprio(1);
#pragma unroll
  for (int ks = 0; ks < 2; ++ks) {
    const bf16x8 ap = *(const bf16x8*)&sP[rowA * 64 + (((ks * 4 + quad) ^ (rowA & 7)) * 8)];
#pragma unroll
    for (int nt = 0; nt < 4; ++nt) {
      const int d  = nt * 16 + li;
      const int gs = (((ks * 4 + quad) ^ (d & 7)) * 8);
      const bf16x8 bv = *(const bf16x8*)&sV[d * 64 + gs];
      acco[nt] = __builtin_amdgcn_mfma_f32_16x16x32_bf16(ap, bv, acco[nt], 0, 0, 0);
    }
  }
  __builtin_amdgcn_s_setprio(0);
}

template <bool PRECONV>
__global__ __launch_bounds__(256, 4)
void seq_attn_kernel(const float* __restrict__ Qf, const float* __restrict__ Kf,
                     const float* __restrict__ Vf, const short* __restrict__ peT,
                     const short* __restrict__ Kb, const short* __restrict__ Vb,
                     float* __restrict__ Out) {
  // sK: K tile (stored-XOR rows); becomes the P buffer after bar3.
  // sV: double-buffered V tiles (slot t&1) so PV(t-1) survives stage(t).
  __shared__ short sK[64 * 64];        // 8KB
  __shared__ short sV[2 * 64 * 64];    // 16KB
  // total 24KB

  const int tid  = threadIdx.x;
  const int w    = tid >> 6;
  const int lane = tid & 63;
  const int li   = lane & 15;
  const int quad = lane >> 4;
  // XCD-aware swizzle: 8 consecutive bh per XCD (Kb+Vb working set = 4MB = L2)
  const int linear = blockIdx.y * 16 + blockIdx.x;
  const int slot   = linear >> 3;
  const int bh     = (linear & 7) * 8 + (slot >> 4);
  const int i0     = (slot & 15) * 64;
  const int rbase  = w * 16 + quad * 4;

  // ---- Q A-fragments, pre-scaled by 0.125*log2(e) so exp2 args are bare adds
  bf16x8 aq[2];
  {
    const float* qp = Qf + (size_t)((bh * MQ + i0 + w * 16 + li) * DH) + quad * 8;
#pragma unroll
    for (int ks = 0; ks < 2; ++ks) {
      float4 f0 = *(const float4*)(qp + ks * 32);
      float4 f1 = *(const float4*)(qp + ks * 32 + 4);
      f0.x *= SCL_LOG2E; f0.y *= SCL_LOG2E; f0.z *= SCL_LOG2E; f0.w *= SCL_LOG2E;
      f1.x *= SCL_LOG2E; f1.y *= SCL_LOG2E; f1.z *= SCL_LOG2E; f1.w *= SCL_LOG2E;
      aq[ks] = mk8(pk2(f0.x, f0.y), pk2(f0.z, f0.w), pk2(f1.x, f1.y), pk2(f1.z, f1.w));
    }
  }

  float l_i[4] = {0.f, 0.f, 0.f, 0.f};
  f32x4 acco[4];
#pragma unroll
  for (int nt = 0; nt < 4; ++nt) acco[nt] = (f32x4){0.f, 0.f, 0.f, 0.f};
  f32x4 prevw3 = (f32x4){0.f, 0.f, 0.f, 0.f};

  if constexpr (PRECONV) {
    // ---- K/V reg-prefetch state (tile t+1 loads fly across compute of t)
    bf16x8 pfK0, pfK1, pfV0, pfV1;
    const short *pK, *pV0, *pV1;
    pK = Kb + ((size_t)bh * NKEY + i0) * DH + tid * 8 + 1024;   // +-1024sh imm
    {
      const int d0 = tid >> 3;
      const int g0 = (tid & 7) ^ (d0 & 7);        // same XOR for slot tid+256
      pV0 = Vb + ((size_t)bh * DH + d0) * NKEY + i0 + g0 * 8;
      pV1 = pV0 + (size_t)32 * NKEY;
    }
    pfK0 = *(const bf16x8*)(pK - 1024);
    pfK1 = *(const bf16x8*)(pK + 1024);
    pfV0 = *(const bf16x8*)(pV0);
    pfV1 = *(const bf16x8*)(pV1);
    pK += 4096; pV0 += 64; pV1 += 64;

    f32x4 csE[4], csO[4];
    unsigned pkE[8], pkO[8];
    bf16x4 pkv[4];

#define STAGE_PF(VSLOT, HAVE_NEXT)                                         \
    do {                                                                   \
      *(bf16x8*)&sK[tid * 8]        = pfK0;                                \
      *(bf16x8*)&sK[tid * 8 + 2048] = pfK1;                                \
      short* sv = sV + (VSLOT) * 4096;                                     \
      *(bf16x8*)&sv[tid * 8]        = pfV0;                                \
      *(bf16x8*)&sv[tid * 8 + 2048] = pfV1;                                \
      if (HAVE_NEXT) {                                                     \
        pfK0 = *(const bf16x8*)(pK - 1024);                                \
        pfK1 = *(const bf16x8*)(pK + 1024);                                \
        pfV0 = *(const bf16x8*)(pV0);                                      \
        pfV1 = *(const bf16x8*)(pV1);                                      \
        pK += 4096; pV0 += 64; pV1 += 64;                                  \
      }                                                                    \
    } while (0)

    for (int tb = 0; tb < 9; ++tb) {
      const int t0 = 2 * tb;
      // ======== phase 0: stage+QK tile t0 (E regs); softmax+PV tile t0-1 (O)
      RAWBAR();                       // all waves' PV/QK reads of sK/sV done
      STAGE_PF(0, tb < 8);            // V slot 0 (t0 even); prefetch t0+1
      RAWBAR();                       // stage visible
      __builtin_amdgcn_s_setprio(1);
      qk_tile(sK, aq, li, quad, csE);
      pe_tile(peT, aq, t0, w, li, quad, pkE);
      __builtin_amdgcn_s_setprio(0);
      if (tb > 0)
        softmax_tile(csO, pkO, prevw3, l_i, pkv, t0 - 1, w, li, quad);
      RAWBAR();                       // bar3: all QK(t0) sK reads retired
      if (tb > 0)
        pv_tile(sK, sV + 4096, pkv, acco, w, li, quad);   // V slot 1 (t0-1 odd)

      // ======== phase 1: stage+QK tile t1 (O regs); softmax+PV tile t0 (E)
      const int t1 = t0 + 1;
      if (tb < 8) {
        RAWBAR();
        STAGE_PF(1, t1 + 1 < NTILE);  // V slot 1 (t1 odd); prefetch t1+1
        RAWBAR();
        __builtin_amdgcn_s_setprio(1);
        qk_tile(sK, aq, li, quad, csO);
        pe_tile(peT, aq, t1, w, li, quad, pkO);
        __builtin_amdgcn_s_setprio(0);
      }
      softmax_tile(csE, pkE, prevw3, l_i, pkv, t0, w, li, quad);
      RAWBAR();                       // bar3 (or plain separator in drain)
      pv_tile(sK, sV, pkv, acco, w, li, quad);            // V slot 0 (t0 even)
    }
#undef STAGE_PF
  } else {
    // ---- fallback: in-kernel f32->bf16 staging, sequential (correctness path)
    for (int t = 0; t < NTILE; ++t) {
      __syncthreads();
      const int j0 = i0 + t * 64;
      {
        const int srow = tid >> 2, l0 = tid & 3, sdb = l0 * 16;
        const float* src = Kf + (size_t)(bh * NKEY + j0 + srow) * DH + sdb;
        const float4 a0 = *(const float4*)(src + 0);
        const float4 a1 = *(const float4*)(src + 4);
        const float4 a2 = *(const float4*)(src + 8);
        const float4 a3 = *(const float4*)(src + 12);
        const bf16x8 b0 = mk8(pk2(a0.x, a0.y), pk2(a0.z, a0.w), pk2(a1.x, a1.y), pk2(a1.z, a1.w));
        const bf16x8 b1 = mk8(pk2(a2.x, a2.y), pk2(a2.z, a2.w), pk2(a3.x, a3.y), pk2(a3.z, a3.w));
        const int s7 = srow & 7;
        *(bf16x8*)&sK[srow * 64 + (((2 * l0)     ^ s7) * 8)] = b0;
        *(bf16x8*)&sK[srow * 64 + (((2 * l0 + 1) ^ s7) * 8)] = b1;
      }
      {
        const int vdb = (tid & 15) * 4, vkb = (tid >> 4) * 4;
        const float* src = Vf + (size_t)(bh * NKEY + j0 + vkb) * DH + vdb;
#pragma unroll
        for (int m = 0; m < 4; ++m) {             // key vkb+m
          const float4 rr = *(const float4*)(src + m * DH);
          const int k   = vkb + m;
          const int kap = (k & 15) * 4 + (k >> 4);
#pragma unroll
          for (int jj = 0; jj < 4; ++jj) {
            const int d = vdb + jj;
            const float fv = (jj == 0) ? rr.x : (jj == 1) ? rr.y : (jj == 2) ? rr.z : rr.w;
            sV[d * 64 + (((kap >> 3) ^ (d & 7)) * 8) + (kap & 7)] = f2bf(fv);
          }
        }
      }
      __syncthreads();

      f32x4 cs[4];
      unsigned pk[8];
      bf16x4 pkv[4];
      qk_tile(sK, aq, li, quad, cs);
      pe_tile(peT, aq, t, w, li, quad, pk);
      softmax_tile(cs, pk, prevw3, l_i, pkv, t, w, li, quad);
      __syncthreads();                // all QK sK reads retired -> P-writable
      pv_tile(sK, sV, pkv, acco, w, li, quad);
    }
  }

  // ---- epilogue: reduce l across the 16 lanes holding each row, out = O / l
#pragma unroll
  for (int r = 0; r < 4; ++r) {
    float l = l_i[r];
    l += __shfl_xor(l, 1);
    l += __shfl_xor(l, 2);
    l += __shfl_xor(l, 4);
    l += __shfl_xor(l, 8);
    const float inv = 1.0f / l;
#pragma unroll
    for (int nt = 0; nt < 4; ++nt) {
      Out[(size_t)(bh * MQ + i0 + rbase + r) * DH + nt * 16 + li] = acco[nt][r] * inv;
    }
  }
}

extern "C" void kernel_launch(void* const* d_in, const int* in_sizes, int n_in,
                              void* d_out, int out_size, void* d_ws, size_t ws_size,
                              hipStream_t stream) {
  const float* q  = (const float*)d_in[0];  // [64,1024,64]
  const float* k  = (const float*)d_in[1];  // [64,2048,64]
  const float* v  = (const float*)d_in[2];  // [64,2048,64]
  const float* pe = (const float*)d_in[3];  // [1,64,1024]
  float* out = (float*)d_out;               // [64,1024,64] f32
  short* peT = (short*)d_ws;
  short* Kb  = (short*)((char*)d_ws + OFF_K);
  short* Vb  = (short*)((char*)d_ws + OFF_V);
  const bool preconv = ws_size >= WS_NEED;  // constant across calls: capture-safe

  dim3 grid(MQ / 64, BHN);
  if (preconv) {
    prep_fused<<<4352, 256, 0, stream>>>(pe, k, v, peT, Kb, Vb);
    seq_attn_kernel<true><<<grid, 256, 0, stream>>>(q, k, v, peT, Kb, Vb, out);
  } else {
    prep_fused<<<256, 256, 0, stream>>>(pe, k, v, peT, Kb, Vb);
    seq_attn_kernel<false><<<grid, 256, 0, stream>>>(q, k, v, peT, Kb, Vb, out);
  }
}

// Round 7
// 197.905 us; speedup vs baseline: 1.4545x; 1.4545x over previous
//
#include <hip/hip_runtime.h>
#include <hip/hip_bf16.h>

// SeqAttention: banded relative-position attention.
// out[b,i,:] = softmax_k( (q_i . key[i+k] + q_i . pe[:,k]) / 8 ) @ value[i+k,:], k in [0,1024)
//
// R14: R11 base (best measured: 68.5us, 64 VGPR, no spill) + PE off the LDS
// pipe. Accounting showed LDS ~80% busy (478 cyc/wave-tile); PE is 120 of
// those (96 fragment-read + 24 staging-write) and its backing table peT is
// 128KB shared by ALL blocks -> the 4KB live window is L1-resident. PE
// fragments now load global->VGPR directly, issued BEFORE the QK phase so
// L1 latency hides under QK's ds_reads+MFMAs. (R12's K/V-direct failure
// doesn't apply: that was 4MB/XCD L2-latency on every operand with nothing
// to hide it.) R13 proved this addressing correct; its regression was
// pipeline-state spill, now reverted. sPE dropped (-16KB LDS), pfP regs
// dropped. K/V reg-prefetch staging, raw barriers, register softmax,
// P-reuses-sK: all byte-identical to R11.
// Spill tripwire: WRITE_SIZE must stay 16384.

typedef __attribute__((ext_vector_type(8))) short bf16x8;
typedef __attribute__((ext_vector_type(4))) short bf16x4;
typedef __attribute__((ext_vector_type(4))) float f32x4;

#define BHN   64
#define MQ    1024
#define DH    64
#define LS    1024
#define NKEY  2048
#define NTILE 17

#define SZ_PE  ((size_t)LS * DH * 2)              // 131072, swizzled bf16 [rel][d]
#define OFF_K  SZ_PE
#define SZ_K   ((size_t)BHN * NKEY * DH * 2)      // bf16, rows pre-swizzled
#define OFF_V  (OFF_K + SZ_K)
#define SZ_V   ((size_t)BHN * DH * NKEY * 2)      // bf16 V^T [bh][d][kappa-key]
#define WS_NEED (OFF_V + SZ_V)                    // ~33.7 MB

// 0.125 (1/sqrt(64)) * log2(e): folded into Q before bf16 cast
#define SCL_LOG2E 0.18033688011112042f

__device__ __forceinline__ short f2bf(float f) {
  unsigned u = __float_as_uint(f);
  u += 0x7FFFu + ((u >> 16) & 1u);                // RNE (inputs finite)
  return (short)(u >> 16);
}
__device__ __forceinline__ float bf2f(short s) {
  return __uint_as_float(((unsigned)(unsigned short)s) << 16);
}

#if defined(__has_builtin)
#if __has_builtin(__builtin_amdgcn_cvt_pk_bf16_f32)
#define HAVE_CVT_PK 1
#endif
#if __has_builtin(__builtin_amdgcn_exp2f)
#define HAVE_EXP2 1
#endif
#endif

__device__ __forceinline__ float fast_exp2(float x) {
#ifdef HAVE_EXP2
  return __builtin_amdgcn_exp2f(x);               // raw v_exp_f32 (args bounded)
#else
  return __builtin_exp2f(x);
#endif
}

// pack two f32 -> two bf16 (RNE) in one unsigned
__device__ __forceinline__ unsigned pk2(float a, float b) {
#ifdef HAVE_CVT_PK
  auto r = __builtin_amdgcn_cvt_pk_bf16_f32(a, b);
  unsigned u;
  __builtin_memcpy(&u, &r, 4);
  return u;
#else
  return (unsigned)(unsigned short)f2bf(a) | ((unsigned)(unsigned short)f2bf(b) << 16);
#endif
}
__device__ __forceinline__ bf16x4 mk4(unsigned a, unsigned b) {
  union { unsigned u[2]; bf16x4 v; } z;
  z.u[0] = a; z.u[1] = b;
  return z.v;
}
__device__ __forceinline__ bf16x8 mk8(unsigned a, unsigned b, unsigned c, unsigned d) {
  union { unsigned u[4]; bf16x8 v; } z;
  z.u[0] = a; z.u[1] = b; z.u[2] = c; z.u[3] = d;
  return z.v;
}

// ---- fused prep: [0,256) PE, [256,2304) K, [2304,4352) V
// PE: [1,D,L] f32 -> peT [rel][d] bf16, granule-swizzled by (rel&7)
// K : [bh*2048][64] f32 -> bf16 rows, granule-swizzled by (row&7)
// V : [bh][2048][64] f32 -> bf16 V^T [bh][64][2048], key dim kappa-permuted
//     per 64-block: kappa = (k&15)*4 + (k>>4)  (inverse k = (kap&3)*16 + (kap>>2))
__global__ __launch_bounds__(256)
void prep_fused(const float* __restrict__ pe, const float* __restrict__ K,
                const float* __restrict__ V, short* __restrict__ peT,
                short* __restrict__ Kb, short* __restrict__ Vb) {
  __shared__ short st[64 * 68];
  const int bx = blockIdx.x;
  if (bx < 256) {
    const int idx = bx * 256 + threadIdx.x;       // 65536
    const int rel = idx >> 6, d = idx & 63;
    peT[rel * 64 + (((d >> 3) ^ (rel & 7)) * 8) + (d & 7)] = f2bf(pe[d * LS + rel]);
  } else if (bx < 2304) {
    const size_t i = ((size_t)(bx - 256) * 256 + threadIdx.x) * 16;  // < 8,388,608
    const int row = (int)(i >> 6);
    const int c16 = (int)(i & 63);                // 0,16,32,48
    const float4 f0 = *(const float4*)(K + i);
    const float4 f1 = *(const float4*)(K + i + 4);
    const float4 f2 = *(const float4*)(K + i + 8);
    const float4 f3 = *(const float4*)(K + i + 12);
    const bf16x8 b0 = mk8(pk2(f0.x, f0.y), pk2(f0.z, f0.w), pk2(f1.x, f1.y), pk2(f1.z, f1.w));
    const bf16x8 b1 = mk8(pk2(f2.x, f2.y), pk2(f2.z, f2.w), pk2(f3.x, f3.y), pk2(f3.z, f3.w));
    const int s7 = row & 7;
    short* dst = Kb + (size_t)row * 64;
    *(bf16x8*)&dst[(((c16 >> 3))     ^ s7) * 8] = b0;
    *(bf16x8*)&dst[(((c16 >> 3) + 1) ^ s7) * 8] = b1;
  } else {
    const int b  = bx - 2304;                     // 0..2047
    const int bh = b >> 5, jt = b & 31;
    {  // phase 1: stage 64x64 tile [key][d], f32->bf16
      const int r = threadIdx.x >> 2, cb = (threadIdx.x & 3) * 16;
      const float* src = V + ((size_t)bh * NKEY + jt * 64 + r) * DH + cb;
#pragma unroll
      for (int c = 0; c < 16; c += 8) {
        float4 f0 = *(const float4*)(src + c);
        float4 f1 = *(const float4*)(src + c + 4);
        *(bf16x8*)&st[r * 68 + cb + c] =
            mk8(pk2(f0.x, f0.y), pk2(f0.z, f0.w), pk2(f1.x, f1.y), pk2(f1.z, f1.w));
      }
    }
    __syncthreads();
    {  // phase 2: transpose + kappa-permute, contiguous b128 writes
      const int d = threadIdx.x >> 2, kapb = (threadIdx.x & 3) * 16;
      __attribute__((aligned(16))) short tmp[16];
#pragma unroll
      for (int j = 0; j < 16; ++j) {
        const int kap = kapb + j;
        const int k   = (kap & 3) * 16 + (kap >> 2);
        tmp[j] = st[k * 68 + d];
      }
      short* dst = Vb + ((size_t)bh * DH + d) * NKEY + jt * 64 + kapb;
      *(bf16x8*)dst       = *(bf16x8*)&tmp[0];
      *(bf16x8*)(dst + 8) = *(bf16x8*)&tmp[8];
    }
  }
}

template <bool PRECONV>
__global__ __launch_bounds__(256, 4)
void seq_attn_kernel(const float* __restrict__ Qf, const float* __restrict__ Kf,
                     const float* __restrict__ Vf, const short* __restrict__ peT,
                     const short* __restrict__ Kb, const short* __restrict__ Vb,
                     float* __restrict__ Out) {
  // stride-64 + granule-XOR layouts: slot = (g ^ (row&7)), g = 16B granule.
  __shared__ short sK[64 * 64];        // [key][d-gran swz]; P after bar3    8KB
  __shared__ short sV[64 * 64];        // [d][kappa-granules swizzled]       8KB
  // total 16KB (PE is global-direct; grid caps residency at 4 blocks/CU)

  const int tid  = threadIdx.x;
  const int w    = tid >> 6;
  const int lane = tid & 63;
  const int li   = lane & 15;
  const int quad = lane >> 4;
  // XCD-aware swizzle: 8 consecutive bh per XCD (Kb+Vb working set = 4MB = L2)
  const int linear = blockIdx.y * 16 + blockIdx.x;
  const int slot   = linear >> 3;
  const int bh     = (linear & 7) * 8 + (slot >> 4);
  const int i0     = (slot & 15) * 64;
  const int rbase  = w * 16 + quad * 4;

  // granule slots within a stored-XOR row (row&7 == li&7 for all our rows)
  const int gsq0 = ((quad) ^ (li & 7)) * 8;       // ks=0
  const int gsq1 = ((4 + quad) ^ (li & 7)) * 8;   // ks=1

  // ---- Q A-fragments, pre-scaled by 0.125*log2(e) so exp2 args are bare adds
  bf16x8 aq[2];
  {
    const float* qp = Qf + (size_t)((bh * MQ + i0 + w * 16 + li) * DH) + quad * 8;
#pragma unroll
    for (int ks = 0; ks < 2; ++ks) {
      float4 f0 = *(const float4*)(qp + ks * 32);
      float4 f1 = *(const float4*)(qp + ks * 32 + 4);
      f0.x *= SCL_LOG2E; f0.y *= SCL_LOG2E; f0.z *= SCL_LOG2E; f0.w *= SCL_LOG2E;
      f1.x *= SCL_LOG2E; f1.y *= SCL_LOG2E; f1.z *= SCL_LOG2E; f1.w *= SCL_LOG2E;
      aq[ks] = mk8(pk2(f0.x, f0.y), pk2(f0.z, f0.w), pk2(f1.x, f1.y), pk2(f1.z, f1.w));
    }
  }

  float l_i[4] = {0.f, 0.f, 0.f, 0.f};
  f32x4 acco[4];
#pragma unroll
  for (int nt = 0; nt < 4; ++nt) acco[nt] = (f32x4){0.f, 0.f, 0.f, 0.f};

  f32x4 curPw[4];   // P over rel cols (4t-w+m)*16.., m=0..3 (per-wave window)
  f32x4 prevw3 = (f32x4){0.f, 0.f, 0.f, 0.f};

  // ---- K/V reg-prefetch state (tile t+1 loads fly across compute of t).
  // LDS dst slots linear (thread tid -> 16B slots tid, tid+256); the V
  // granule-XOR is applied on the SOURCE address (t-invariant per thread).
  bf16x8 pfK0, pfK1, pfV0, pfV1;
  const short *pK, *pV0, *pV1;
  if constexpr (PRECONV) {
    pK = Kb + ((size_t)bh * NKEY + i0) * DH + tid * 8 + 1024;   // +-1024sh imm
    const int d0 = tid >> 3;
    const int g0 = (tid & 7) ^ (d0 & 7);          // same XOR for slot tid+256
    pV0 = Vb + ((size_t)bh * DH + d0) * NKEY + i0 + g0 * 8;
    pV1 = pV0 + (size_t)32 * NKEY;
    pfK0 = *(const bf16x8*)(pK - 1024);
    pfK1 = *(const bf16x8*)(pK + 1024);
    pfV0 = *(const bf16x8*)(pV0);
    pfV1 = *(const bf16x8*)(pV1);
    pK += 4096; pV0 += 64; pV1 += 64;
  }

  for (int t = 0; t < NTILE; ++t) {
    if constexpr (PRECONV) {
      // Raw entry barrier: previous tile's PV sK/sV reads retired; pf-reg
      // vmcnt waits happen per-wave at the ds_writes below.
      asm volatile("s_waitcnt lgkmcnt(0)" ::: "memory");
      __builtin_amdgcn_sched_barrier(0);
      __builtin_amdgcn_s_barrier();
      __builtin_amdgcn_sched_barrier(0);
      // ---- ds_write staged tile t (linear, stride-16B, conflict-free)
      *(bf16x8*)&sK[tid * 8]        = pfK0;
      *(bf16x8*)&sK[tid * 8 + 2048] = pfK1;
      *(bf16x8*)&sV[tid * 8]        = pfV0;
      *(bf16x8*)&sV[tid * 8 + 2048] = pfV1;
      // ---- issue K/V prefetch for tile t+1; flies across the raw barriers
      // and both compute phases (waited at next tile's ds_writes)
      if (t + 1 < NTILE) {
        pfK0 = *(const bf16x8*)(pK - 1024);
        pfK1 = *(const bf16x8*)(pK + 1024);
        pfV0 = *(const bf16x8*)(pV0);
        pfV1 = *(const bf16x8*)(pV1);
        pK += 4096; pV0 += 64; pV1 += 64;
      }
      // RAW barrier: wait only on LDS writes, NOT vmem — prefetch flies.
      asm volatile("s_waitcnt lgkmcnt(0)" ::: "memory");
      __builtin_amdgcn_sched_barrier(0);
      __builtin_amdgcn_s_barrier();
      __builtin_amdgcn_sched_barrier(0);
    } else {
      // ---- fallback: stage with in-kernel f32->bf16 conversion
      __syncthreads();
      const int j0 = i0 + t * 64;
      {
        const int srow = tid >> 2, l0 = tid & 3, sdb = l0 * 16;
        const float* src = Kf + (size_t)(bh * NKEY + j0 + srow) * DH + sdb;
        const float4 a0 = *(const float4*)(src + 0);
        const float4 a1 = *(const float4*)(src + 4);
        const float4 a2 = *(const float4*)(src + 8);
        const float4 a3 = *(const float4*)(src + 12);
        const bf16x8 b0 = mk8(pk2(a0.x, a0.y), pk2(a0.z, a0.w), pk2(a1.x, a1.y), pk2(a1.z, a1.w));
        const bf16x8 b1 = mk8(pk2(a2.x, a2.y), pk2(a2.z, a2.w), pk2(a3.x, a3.y), pk2(a3.z, a3.w));
        const int s7 = srow & 7;
        *(bf16x8*)&sK[srow * 64 + (((2 * l0)     ^ s7) * 8)] = b0;
        *(bf16x8*)&sK[srow * 64 + (((2 * l0 + 1) ^ s7) * 8)] = b1;
      }
      {
        const int vdb = (tid & 15) * 4, vkb = (tid >> 4) * 4;
        const float* src = Vf + (size_t)(bh * NKEY + j0 + vkb) * DH + vdb;
#pragma unroll
        for (int m = 0; m < 4; ++m) {             // key vkb+m
          const float4 rr = *(const float4*)(src + m * DH);
          const int k   = vkb + m;
          const int kap = (k & 15) * 4 + (k >> 4);
#pragma unroll
          for (int jj = 0; jj < 4; ++jj) {
            const int d = vdb + jj;
            const float fv = (jj == 0) ? rr.x : (jj == 1) ? rr.y : (jj == 2) ? rr.z : rr.w;
            sV[d * 64 + (((kap >> 3) ^ (d & 7)) * 8) + (kap & 7)] = f2bf(fv);
          }
        }
      }
      __syncthreads();
    }

    // ---- PE fragments DIRECT from peT (L1-hot: 4KB live window shared by
    // every wave on the CU). Issued BEFORE the QK phase so the hit latency
    // hides under QK's ds_reads+MFMAs. colIdx clamped to [0,63]; clamped
    // windows only feed band-masked lanes (same invariant as the old
    // stale-LDS reads; R13 verified this addressing end-to-end).
    bf16x8 fp0[4], fp1[4];
#pragma unroll
    for (int m = 0; m < 4; ++m) {
      int cidx = 4 * t - w + m;
      cidx = cidx < 0 ? 0 : (cidx > 63 ? 63 : cidx);
      const short* p = peT + (size_t)(cidx * 16 + li) * 64;  // rel&7 == li&7
      fp0[m] = *(const bf16x8*)(p + gsq0);
      fp1[m] = *(const bf16x8*)(p + gsq1);
    }

    // ---- S = Q @ K^T from LDS (Q pre-scaled, so cs is in log2-units)
    f32x4 cs[4];
    __builtin_amdgcn_s_setprio(1);
#pragma unroll
    for (int nt = 0; nt < 4; ++nt) {
      const int row = (nt * 16 + li) * 64;
      f32x4 c = (f32x4){0.f, 0.f, 0.f, 0.f};
      c = __builtin_amdgcn_mfma_f32_16x16x32_bf16(aq[0], *(const bf16x8*)&sK[row + gsq0], c, 0, 0, 0);
      c = __builtin_amdgcn_mfma_f32_16x16x32_bf16(aq[1], *(const bf16x8*)&sK[row + gsq1], c, 0, 0, 0);
      cs[nt] = c;
    }

    // ---- curPw[m] = Q @ PE from the direct-loaded fragments
#pragma unroll
    for (int m = 0; m < 4; ++m) {
      f32x4 c = (f32x4){0.f, 0.f, 0.f, 0.f};
      c = __builtin_amdgcn_mfma_f32_16x16x32_bf16(aq[0], fp0[m], c, 0, 0, 0);
      c = __builtin_amdgcn_mfma_f32_16x16x32_bf16(aq[1], fp1[m], c, 0, 0, 0);
      curPw[m] = c;
    }
    __builtin_amdgcn_s_setprio(0);

    // ---- register-phase softmax: diagonal gather (3 packed shuffles per r)
    // + no-max exp2; produces pkv[4] (8 VGPRs). cs/cur die HERE — only pkv
    // crosses bar3 (small live set: R10/R13 spill lesson).
    bf16x4 pkv[4];
#pragma unroll
    for (int r = 0; r < 4; ++r) {
      const int e       = li - quad * 4 - r;          // in [-15, 15]
      const bool ge     = (e >= 0);
      const int srcLane = quad * 16 + (e & 15);
      const float shm = __shfl(prevw3[r], srcLane);
      const unsigned pk01 = pk2(curPw[0][r], curPw[1][r]);
      const unsigned pk23 = pk2(curPw[2][r], curPw[3][r]);
      const unsigned s01 = (unsigned)__shfl((int)pk01, srcLane);
      const unsigned s23 = (unsigned)__shfl((int)pk23, srcLane);
      const float sh0 = bf2f((short)(s01 & 0xffffu));
      const float sh1 = bf2f((short)(s01 >> 16));
      const float sh2 = bf2f((short)(s23 & 0xffffu));
      const float sh3 = bf2f((short)(s23 >> 16));
      const float pos0 = ge ? sh0 : shm;
      const float pos1 = ge ? sh1 : sh0;
      const float pos2 = ge ? sh2 : sh1;
      const float pos3 = ge ? sh3 : sh2;
      float p0 = fast_exp2(cs[0][r] + pos0);
      float p1 = fast_exp2(cs[1][r] + pos1);
      float p2 = fast_exp2(cs[2][r] + pos2);
      float p3 = fast_exp2(cs[3][r] + pos3);
      if (t == 0) {                 // valid iff dl>=0: nt>w || (nt==w && ge)
        p0 = (0 > w || (0 == w && ge)) ? p0 : 0.f;
        p1 = (1 > w || (1 == w && ge)) ? p1 : 0.f;
        p2 = (2 > w || (2 == w && ge)) ? p2 : 0.f;
        p3 = (3 > w || (3 == w && ge)) ? p3 : 0.f;
      } else if (t == NTILE - 1) {  // valid iff dl<0: nt<w || (nt==w && !ge)
        p0 = (0 < w || (0 == w && !ge)) ? p0 : 0.f;
        p1 = (1 < w || (1 == w && !ge)) ? p1 : 0.f;
        p2 = (2 < w || (2 == w && !ge)) ? p2 : 0.f;
        p3 = (3 < w || (3 == w && !ge)) ? p3 : 0.f;
      }
      l_i[r] += (p0 + p1) + (p2 + p3);
      pkv[r] = mk4(pk2(p0, p1), pk2(p2, p3));
    }
    prevw3 = curPw[3];

    // ---- bar3: all waves' QK^T sK reads + shuffles retired -> sK becomes
    // the P buffer (stripes wave-private: wave w rows w*16..w*16+15).
    asm volatile("s_waitcnt lgkmcnt(0)" ::: "memory");
    __builtin_amdgcn_sched_barrier(0);
    __builtin_amdgcn_s_barrier();
    __builtin_amdgcn_sched_barrier(0);

    // kappa-order store: lane li's keys nt*16+li -> kappa = 4*li + nt,
    // contiguous => one b64. Granule (li>>1) ^ (rowA&7), offset (li&1)*4.
#pragma unroll
    for (int r = 0; r < 4; ++r) {
      const int rowA = rbase + r;
      *(bf16x4*)&sK[rowA * 64 + (((li >> 1) ^ (rowA & 7)) * 8) + (li & 1) * 4] = pkv[r];
    }

    // ---- O += P @ V  (kappa-ordered contraction on both operands)
    __builtin_amdgcn_s_setprio(1);
#pragma unroll
    for (int ks = 0; ks < 2; ++ks) {
      const int rowA = w * 16 + li;
      const bf16x8 ap =
          *(bf16x8*)&sK[rowA * 64 + (((ks * 4 + quad) ^ (rowA & 7)) * 8)];
#pragma unroll
      for (int nt = 0; nt < 4; ++nt) {
        const int d  = nt * 16 + li;
        const int gs = (((ks * 4 + quad) ^ (d & 7)) * 8);
        const bf16x8 bv = *(bf16x8*)&sV[d * 64 + gs];
        acco[nt] = __builtin_amdgcn_mfma_f32_16x16x32_bf16(ap, bv, acco[nt], 0, 0, 0);
      }
    }
    __builtin_amdgcn_s_setprio(0);
  }

  // ---- epilogue: reduce l across the 16 lanes holding each row, out = O / l
#pragma unroll
  for (int r = 0; r < 4; ++r) {
    float l = l_i[r];
    l += __shfl_xor(l, 1);
    l += __shfl_xor(l, 2);
    l += __shfl_xor(l, 4);
    l += __shfl_xor(l, 8);
    const float inv = 1.0f / l;
#pragma unroll
    for (int nt = 0; nt < 4; ++nt) {
      Out[(size_t)(bh * MQ + i0 + rbase + r) * DH + nt * 16 + li] = acco[nt][r] * inv;
    }
  }
}

extern "C" void kernel_launch(void* const* d_in, const int* in_sizes, int n_in,
                              void* d_out, int out_size, void* d_ws, size_t ws_size,
                              hipStream_t stream) {
  const float* q  = (const float*)d_in[0];  // [64,1024,64]
  const float* k  = (const float*)d_in[1];  // [64,2048,64]
  const float* v  = (const float*)d_in[2];  // [64,2048,64]
  const float* pe = (const float*)d_in[3];  // [1,64,1024]
  float* out = (float*)d_out;               // [64,1024,64] f32
  short* peT = (short*)d_ws;
  short* Kb  = (short*)((char*)d_ws + OFF_K);
  short* Vb  = (short*)((char*)d_ws + OFF_V);
  const bool preconv = ws_size >= WS_NEED;  // constant across calls: capture-safe

  dim3 grid(MQ / 64, BHN);
  if (preconv) {
    prep_fused<<<4352, 256, 0, stream>>>(pe, k, v, peT, Kb, Vb);
    seq_attn_kernel<true><<<grid, 256, 0, stream>>>(q, k, v, peT, Kb, Vb, out);
  } else {
    prep_fused<<<256, 256, 0, stream>>>(pe, k, v, peT, Kb, Vb);
    seq_attn_kernel<false><<<grid, 256, 0, stream>>>(q, k, v, peT, Kb, Vb, out);
  }
}

// Round 8
// 184.833 us; speedup vs baseline: 1.5574x; 1.0707x over previous
//
#include <hip/hip_runtime.h>
#include <hip/hip_bf16.h>

// SeqAttention: banded relative-position attention.
// out[b,i,:] = softmax_k( (q_i . key[i+k] + q_i . pe[:,k]) / 8 ) @ value[i+k,:], k in [0,1024)
//
// R15: R14 (PE fragments global-direct from L1-hot peT; sPE dropped) with
// ONE fix: __launch_bounds__(256, 2). R14's 81MB of extra HBM writes was a
// ~4-reg/tile scratch spill at VGPR_Count=64 — LLVM's AMDGPU scheduler
// targets 8-waves/SIMD (64 VGPR) and accepts small spills; launch_bounds'
// 2nd arg only sets a MINIMUM. Bound 2 waves/EU -> 256-reg cap lets the
// ~114-reg peak live set (pf 32 + aq 16 + acco 16 + 8 PE fragments 32 +
// addr/misc) stay in registers. Expected VGPR ~100-128 (grid still caps
// residency at 4 blocks/CU = 4 waves/SIMD if <=128).
// R14's PE-cache premise was CONFIRMED (FETCH +4.4MB over 570MB of PE load
// traffic = >99% hit); only the spill regressed. Everything else identical
// to R11 (best measured no-spill base: 68.5us).
// Spill tripwire: WRITE_SIZE must be 16384.

typedef __attribute__((ext_vector_type(8))) short bf16x8;
typedef __attribute__((ext_vector_type(4))) short bf16x4;
typedef __attribute__((ext_vector_type(4))) float f32x4;

#define BHN   64
#define MQ    1024
#define DH    64
#define LS    1024
#define NKEY  2048
#define NTILE 17

#define SZ_PE  ((size_t)LS * DH * 2)              // 131072, swizzled bf16 [rel][d]
#define OFF_K  SZ_PE
#define SZ_K   ((size_t)BHN * NKEY * DH * 2)      // bf16, rows pre-swizzled
#define OFF_V  (OFF_K + SZ_K)
#define SZ_V   ((size_t)BHN * DH * NKEY * 2)      // bf16 V^T [bh][d][kappa-key]
#define WS_NEED (OFF_V + SZ_V)                    // ~33.7 MB

// 0.125 (1/sqrt(64)) * log2(e): folded into Q before bf16 cast
#define SCL_LOG2E 0.18033688011112042f

__device__ __forceinline__ short f2bf(float f) {
  unsigned u = __float_as_uint(f);
  u += 0x7FFFu + ((u >> 16) & 1u);                // RNE (inputs finite)
  return (short)(u >> 16);
}
__device__ __forceinline__ float bf2f(short s) {
  return __uint_as_float(((unsigned)(unsigned short)s) << 16);
}

#if defined(__has_builtin)
#if __has_builtin(__builtin_amdgcn_cvt_pk_bf16_f32)
#define HAVE_CVT_PK 1
#endif
#if __has_builtin(__builtin_amdgcn_exp2f)
#define HAVE_EXP2 1
#endif
#endif

__device__ __forceinline__ float fast_exp2(float x) {
#ifdef HAVE_EXP2
  return __builtin_amdgcn_exp2f(x);               // raw v_exp_f32 (args bounded)
#else
  return __builtin_exp2f(x);
#endif
}

// pack two f32 -> two bf16 (RNE) in one unsigned
__device__ __forceinline__ unsigned pk2(float a, float b) {
#ifdef HAVE_CVT_PK
  auto r = __builtin_amdgcn_cvt_pk_bf16_f32(a, b);
  unsigned u;
  __builtin_memcpy(&u, &r, 4);
  return u;
#else
  return (unsigned)(unsigned short)f2bf(a) | ((unsigned)(unsigned short)f2bf(b) << 16);
#endif
}
__device__ __forceinline__ bf16x4 mk4(unsigned a, unsigned b) {
  union { unsigned u[2]; bf16x4 v; } z;
  z.u[0] = a; z.u[1] = b;
  return z.v;
}
__device__ __forceinline__ bf16x8 mk8(unsigned a, unsigned b, unsigned c, unsigned d) {
  union { unsigned u[4]; bf16x8 v; } z;
  z.u[0] = a; z.u[1] = b; z.u[2] = c; z.u[3] = d;
  return z.v;
}

// ---- fused prep: [0,256) PE, [256,2304) K, [2304,4352) V
// PE: [1,D,L] f32 -> peT [rel][d] bf16, granule-swizzled by (rel&7)
// K : [bh*2048][64] f32 -> bf16 rows, granule-swizzled by (row&7)
// V : [bh][2048][64] f32 -> bf16 V^T [bh][64][2048], key dim kappa-permuted
//     per 64-block: kappa = (k&15)*4 + (k>>4)  (inverse k = (kap&3)*16 + (kap>>2))
__global__ __launch_bounds__(256)
void prep_fused(const float* __restrict__ pe, const float* __restrict__ K,
                const float* __restrict__ V, short* __restrict__ peT,
                short* __restrict__ Kb, short* __restrict__ Vb) {
  __shared__ short st[64 * 68];
  const int bx = blockIdx.x;
  if (bx < 256) {
    const int idx = bx * 256 + threadIdx.x;       // 65536
    const int rel = idx >> 6, d = idx & 63;
    peT[rel * 64 + (((d >> 3) ^ (rel & 7)) * 8) + (d & 7)] = f2bf(pe[d * LS + rel]);
  } else if (bx < 2304) {
    const size_t i = ((size_t)(bx - 256) * 256 + threadIdx.x) * 16;  // < 8,388,608
    const int row = (int)(i >> 6);
    const int c16 = (int)(i & 63);                // 0,16,32,48
    const float4 f0 = *(const float4*)(K + i);
    const float4 f1 = *(const float4*)(K + i + 4);
    const float4 f2 = *(const float4*)(K + i + 8);
    const float4 f3 = *(const float4*)(K + i + 12);
    const bf16x8 b0 = mk8(pk2(f0.x, f0.y), pk2(f0.z, f0.w), pk2(f1.x, f1.y), pk2(f1.z, f1.w));
    const bf16x8 b1 = mk8(pk2(f2.x, f2.y), pk2(f2.z, f2.w), pk2(f3.x, f3.y), pk2(f3.z, f3.w));
    const int s7 = row & 7;
    short* dst = Kb + (size_t)row * 64;
    *(bf16x8*)&dst[(((c16 >> 3))     ^ s7) * 8] = b0;
    *(bf16x8*)&dst[(((c16 >> 3) + 1) ^ s7) * 8] = b1;
  } else {
    const int b  = bx - 2304;                     // 0..2047
    const int bh = b >> 5, jt = b & 31;
    {  // phase 1: stage 64x64 tile [key][d], f32->bf16
      const int r = threadIdx.x >> 2, cb = (threadIdx.x & 3) * 16;
      const float* src = V + ((size_t)bh * NKEY + jt * 64 + r) * DH + cb;
#pragma unroll
      for (int c = 0; c < 16; c += 8) {
        float4 f0 = *(const float4*)(src + c);
        float4 f1 = *(const float4*)(src + c + 4);
        *(bf16x8*)&st[r * 68 + cb + c] =
            mk8(pk2(f0.x, f0.y), pk2(f0.z, f0.w), pk2(f1.x, f1.y), pk2(f1.z, f1.w));
      }
    }
    __syncthreads();
    {  // phase 2: transpose + kappa-permute, contiguous b128 writes
      const int d = threadIdx.x >> 2, kapb = (threadIdx.x & 3) * 16;
      __attribute__((aligned(16))) short tmp[16];
#pragma unroll
      for (int j = 0; j < 16; ++j) {
        const int kap = kapb + j;
        const int k   = (kap & 3) * 16 + (kap >> 2);
        tmp[j] = st[k * 68 + d];
      }
      short* dst = Vb + ((size_t)bh * DH + d) * NKEY + jt * 64 + kapb;
      *(bf16x8*)dst       = *(bf16x8*)&tmp[0];
      *(bf16x8*)(dst + 8) = *(bf16x8*)&tmp[8];
    }
  }
}

template <bool PRECONV>
__global__ __launch_bounds__(256, 2)
void seq_attn_kernel(const float* __restrict__ Qf, const float* __restrict__ Kf,
                     const float* __restrict__ Vf, const short* __restrict__ peT,
                     const short* __restrict__ Kb, const short* __restrict__ Vb,
                     float* __restrict__ Out) {
  // stride-64 + granule-XOR layouts: slot = (g ^ (row&7)), g = 16B granule.
  __shared__ short sK[64 * 64];        // [key][d-gran swz]; P after bar3    8KB
  __shared__ short sV[64 * 64];        // [d][kappa-granules swizzled]       8KB
  // total 16KB (PE is global-direct; grid caps residency at 4 blocks/CU)

  const int tid  = threadIdx.x;
  const int w    = tid >> 6;
  const int lane = tid & 63;
  const int li   = lane & 15;
  const int quad = lane >> 4;
  // XCD-aware swizzle: 8 consecutive bh per XCD (Kb+Vb working set = 4MB = L2)
  const int linear = blockIdx.y * 16 + blockIdx.x;
  const int slot   = linear >> 3;
  const int bh     = (linear & 7) * 8 + (slot >> 4);
  const int i0     = (slot & 15) * 64;
  const int rbase  = w * 16 + quad * 4;

  // granule slots within a stored-XOR row (row&7 == li&7 for all our rows)
  const int gsq0 = ((quad) ^ (li & 7)) * 8;       // ks=0
  const int gsq1 = ((4 + quad) ^ (li & 7)) * 8;   // ks=1

  // ---- Q A-fragments, pre-scaled by 0.125*log2(e) so exp2 args are bare adds
  bf16x8 aq[2];
  {
    const float* qp = Qf + (size_t)((bh * MQ + i0 + w * 16 + li) * DH) + quad * 8;
#pragma unroll
    for (int ks = 0; ks < 2; ++ks) {
      float4 f0 = *(const float4*)(qp + ks * 32);
      float4 f1 = *(const float4*)(qp + ks * 32 + 4);
      f0.x *= SCL_LOG2E; f0.y *= SCL_LOG2E; f0.z *= SCL_LOG2E; f0.w *= SCL_LOG2E;
      f1.x *= SCL_LOG2E; f1.y *= SCL_LOG2E; f1.z *= SCL_LOG2E; f1.w *= SCL_LOG2E;
      aq[ks] = mk8(pk2(f0.x, f0.y), pk2(f0.z, f0.w), pk2(f1.x, f1.y), pk2(f1.z, f1.w));
    }
  }

  float l_i[4] = {0.f, 0.f, 0.f, 0.f};
  f32x4 acco[4];
#pragma unroll
  for (int nt = 0; nt < 4; ++nt) acco[nt] = (f32x4){0.f, 0.f, 0.f, 0.f};

  f32x4 curPw[4];   // P over rel cols (4t-w+m)*16.., m=0..3 (per-wave window)
  f32x4 prevw3 = (f32x4){0.f, 0.f, 0.f, 0.f};

  // ---- K/V reg-prefetch state (tile t+1 loads fly across compute of t).
  // LDS dst slots linear (thread tid -> 16B slots tid, tid+256); the V
  // granule-XOR is applied on the SOURCE address (t-invariant per thread).
  bf16x8 pfK0, pfK1, pfV0, pfV1;
  const short *pK, *pV0, *pV1;
  if constexpr (PRECONV) {
    pK = Kb + ((size_t)bh * NKEY + i0) * DH + tid * 8 + 1024;   // +-1024sh imm
    const int d0 = tid >> 3;
    const int g0 = (tid & 7) ^ (d0 & 7);          // same XOR for slot tid+256
    pV0 = Vb + ((size_t)bh * DH + d0) * NKEY + i0 + g0 * 8;
    pV1 = pV0 + (size_t)32 * NKEY;
    pfK0 = *(const bf16x8*)(pK - 1024);
    pfK1 = *(const bf16x8*)(pK + 1024);
    pfV0 = *(const bf16x8*)(pV0);
    pfV1 = *(const bf16x8*)(pV1);
    pK += 4096; pV0 += 64; pV1 += 64;
  }

  for (int t = 0; t < NTILE; ++t) {
    if constexpr (PRECONV) {
      // Raw entry barrier: previous tile's PV sK/sV reads retired; pf-reg
      // vmcnt waits happen per-wave at the ds_writes below.
      asm volatile("s_waitcnt lgkmcnt(0)" ::: "memory");
      __builtin_amdgcn_sched_barrier(0);
      __builtin_amdgcn_s_barrier();
      __builtin_amdgcn_sched_barrier(0);
      // ---- ds_write staged tile t (linear, stride-16B, conflict-free)
      *(bf16x8*)&sK[tid * 8]        = pfK0;
      *(bf16x8*)&sK[tid * 8 + 2048] = pfK1;
      *(bf16x8*)&sV[tid * 8]        = pfV0;
      *(bf16x8*)&sV[tid * 8 + 2048] = pfV1;
      // ---- issue K/V prefetch for tile t+1; flies across the raw barriers
      // and both compute phases (waited at next tile's ds_writes)
      if (t + 1 < NTILE) {
        pfK0 = *(const bf16x8*)(pK - 1024);
        pfK1 = *(const bf16x8*)(pK + 1024);
        pfV0 = *(const bf16x8*)(pV0);
        pfV1 = *(const bf16x8*)(pV1);
        pK += 4096; pV0 += 64; pV1 += 64;
      }
      // RAW barrier: wait only on LDS writes, NOT vmem — prefetch flies.
      asm volatile("s_waitcnt lgkmcnt(0)" ::: "memory");
      __builtin_amdgcn_sched_barrier(0);
      __builtin_amdgcn_s_barrier();
      __builtin_amdgcn_sched_barrier(0);
    } else {
      // ---- fallback: stage with in-kernel f32->bf16 conversion
      __syncthreads();
      const int j0 = i0 + t * 64;
      {
        const int srow = tid >> 2, l0 = tid & 3, sdb = l0 * 16;
        const float* src = Kf + (size_t)(bh * NKEY + j0 + srow) * DH + sdb;
        const float4 a0 = *(const float4*)(src + 0);
        const float4 a1 = *(const float4*)(src + 4);
        const float4 a2 = *(const float4*)(src + 8);
        const float4 a3 = *(const float4*)(src + 12);
        const bf16x8 b0 = mk8(pk2(a0.x, a0.y), pk2(a0.z, a0.w), pk2(a1.x, a1.y), pk2(a1.z, a1.w));
        const bf16x8 b1 = mk8(pk2(a2.x, a2.y), pk2(a2.z, a2.w), pk2(a3.x, a3.y), pk2(a3.z, a3.w));
        const int s7 = srow & 7;
        *(bf16x8*)&sK[srow * 64 + (((2 * l0)     ^ s7) * 8)] = b0;
        *(bf16x8*)&sK[srow * 64 + (((2 * l0 + 1) ^ s7) * 8)] = b1;
      }
      {
        const int vdb = (tid & 15) * 4, vkb = (tid >> 4) * 4;
        const float* src = Vf + (size_t)(bh * NKEY + j0 + vkb) * DH + vdb;
#pragma unroll
        for (int m = 0; m < 4; ++m) {             // key vkb+m
          const float4 rr = *(const float4*)(src + m * DH);
          const int k   = vkb + m;
          const int kap = (k & 15) * 4 + (k >> 4);
#pragma unroll
          for (int jj = 0; jj < 4; ++jj) {
            const int d = vdb + jj;
            const float fv = (jj == 0) ? rr.x : (jj == 1) ? rr.y : (jj == 2) ? rr.z : rr.w;
            sV[d * 64 + (((kap >> 3) ^ (d & 7)) * 8) + (kap & 7)] = f2bf(fv);
          }
        }
      }
      __syncthreads();
    }

    // ---- PE fragments DIRECT from peT (L1-hot: 4KB live window shared by
    // every wave on the CU; R14 confirmed >99% cache hit). Issued BEFORE the
    // QK phase so the hit latency hides under QK's ds_reads+MFMAs. colIdx
    // clamped to [0,63]; clamped windows only feed band-masked lanes.
    bf16x8 fp0[4], fp1[4];
#pragma unroll
    for (int m = 0; m < 4; ++m) {
      int cidx = 4 * t - w + m;
      cidx = cidx < 0 ? 0 : (cidx > 63 ? 63 : cidx);
      const short* p = peT + (size_t)(cidx * 16 + li) * 64;  // rel&7 == li&7
      fp0[m] = *(const bf16x8*)(p + gsq0);
      fp1[m] = *(const bf16x8*)(p + gsq1);
    }

    // ---- S = Q @ K^T from LDS (Q pre-scaled, so cs is in log2-units)
    f32x4 cs[4];
    __builtin_amdgcn_s_setprio(1);
#pragma unroll
    for (int nt = 0; nt < 4; ++nt) {
      const int row = (nt * 16 + li) * 64;
      f32x4 c = (f32x4){0.f, 0.f, 0.f, 0.f};
      c = __builtin_amdgcn_mfma_f32_16x16x32_bf16(aq[0], *(const bf16x8*)&sK[row + gsq0], c, 0, 0, 0);
      c = __builtin_amdgcn_mfma_f32_16x16x32_bf16(aq[1], *(const bf16x8*)&sK[row + gsq1], c, 0, 0, 0);
      cs[nt] = c;
    }

    // ---- curPw[m] = Q @ PE from the direct-loaded fragments
#pragma unroll
    for (int m = 0; m < 4; ++m) {
      f32x4 c = (f32x4){0.f, 0.f, 0.f, 0.f};
      c = __builtin_amdgcn_mfma_f32_16x16x32_bf16(aq[0], fp0[m], c, 0, 0, 0);
      c = __builtin_amdgcn_mfma_f32_16x16x32_bf16(aq[1], fp1[m], c, 0, 0, 0);
      curPw[m] = c;
    }
    __builtin_amdgcn_s_setprio(0);

    // ---- register-phase softmax: diagonal gather (3 packed shuffles per r)
    // + no-max exp2; produces pkv[4] (8 VGPRs). cs/cur die HERE — only pkv
    // crosses bar3 (small live set: R10/R13 spill lesson).
    bf16x4 pkv[4];
#pragma unroll
    for (int r = 0; r < 4; ++r) {
      const int e       = li - quad * 4 - r;          // in [-15, 15]
      const bool ge     = (e >= 0);
      const int srcLane = quad * 16 + (e & 15);
      const float shm = __shfl(prevw3[r], srcLane);
      const unsigned pk01 = pk2(curPw[0][r], curPw[1][r]);
      const unsigned pk23 = pk2(curPw[2][r], curPw[3][r]);
      const unsigned s01 = (unsigned)__shfl((int)pk01, srcLane);
      const unsigned s23 = (unsigned)__shfl((int)pk23, srcLane);
      const float sh0 = bf2f((short)(s01 & 0xffffu));
      const float sh1 = bf2f((short)(s01 >> 16));
      const float sh2 = bf2f((short)(s23 & 0xffffu));
      const float sh3 = bf2f((short)(s23 >> 16));
      const float pos0 = ge ? sh0 : shm;
      const float pos1 = ge ? sh1 : sh0;
      const float pos2 = ge ? sh2 : sh1;
      const float pos3 = ge ? sh3 : sh2;
      float p0 = fast_exp2(cs[0][r] + pos0);
      float p1 = fast_exp2(cs[1][r] + pos1);
      float p2 = fast_exp2(cs[2][r] + pos2);
      float p3 = fast_exp2(cs[3][r] + pos3);
      if (t == 0) {                 // valid iff dl>=0: nt>w || (nt==w && ge)
        p0 = (0 > w || (0 == w && ge)) ? p0 : 0.f;
        p1 = (1 > w || (1 == w && ge)) ? p1 : 0.f;
        p2 = (2 > w || (2 == w && ge)) ? p2 : 0.f;
        p3 = (3 > w || (3 == w && ge)) ? p3 : 0.f;
      } else if (t == NTILE - 1) {  // valid iff dl<0: nt<w || (nt==w && !ge)
        p0 = (0 < w || (0 == w && !ge)) ? p0 : 0.f;
        p1 = (1 < w || (1 == w && !ge)) ? p1 : 0.f;
        p2 = (2 < w || (2 == w && !ge)) ? p2 : 0.f;
        p3 = (3 < w || (3 == w && !ge)) ? p3 : 0.f;
      }
      l_i[r] += (p0 + p1) + (p2 + p3);
      pkv[r] = mk4(pk2(p0, p1), pk2(p2, p3));
    }
    prevw3 = curPw[3];

    // ---- bar3: all waves' QK^T sK reads + shuffles retired -> sK becomes
    // the P buffer (stripes wave-private: wave w rows w*16..w*16+15).
    asm volatile("s_waitcnt lgkmcnt(0)" ::: "memory");
    __builtin_amdgcn_sched_barrier(0);
    __builtin_amdgcn_s_barrier();
    __builtin_amdgcn_sched_barrier(0);

    // kappa-order store: lane li's keys nt*16+li -> kappa = 4*li + nt,
    // contiguous => one b64. Granule (li>>1) ^ (rowA&7), offset (li&1)*4.
#pragma unroll
    for (int r = 0; r < 4; ++r) {
      const int rowA = rbase + r;
      *(bf16x4*)&sK[rowA * 64 + (((li >> 1) ^ (rowA & 7)) * 8) + (li & 1) * 4] = pkv[r];
    }

    // ---- O += P @ V  (kappa-ordered contraction on both operands)
    __builtin_amdgcn_s_setprio(1);
#pragma unroll
    for (int ks = 0; ks < 2; ++ks) {
      const int rowA = w * 16 + li;
      const bf16x8 ap =
          *(bf16x8*)&sK[rowA * 64 + (((ks * 4 + quad) ^ (rowA & 7)) * 8)];
#pragma unroll
      for (int nt = 0; nt < 4; ++nt) {
        const int d  = nt * 16 + li;
        const int gs = (((ks * 4 + quad) ^ (d & 7)) * 8);
        const bf16x8 bv = *(bf16x8*)&sV[d * 64 + gs];
        acco[nt] = __builtin_amdgcn_mfma_f32_16x16x32_bf16(ap, bv, acco[nt], 0, 0, 0);
      }
    }
    __builtin_amdgcn_s_setprio(0);
  }

  // ---- epilogue: reduce l across the 16 lanes holding each row, out = O / l
#pragma unroll
  for (int r = 0; r < 4; ++r) {
    float l = l_i[r];
    l += __shfl_xor(l, 1);
    l += __shfl_xor(l, 2);
    l += __shfl_xor(l, 4);
    l += __shfl_xor(l, 8);
    const float inv = 1.0f / l;
#pragma unroll
    for (int nt = 0; nt < 4; ++nt) {
      Out[(size_t)(bh * MQ + i0 + rbase + r) * DH + nt * 16 + li] = acco[nt][r] * inv;
    }
  }
}

extern "C" void kernel_launch(void* const* d_in, const int* in_sizes, int n_in,
                              void* d_out, int out_size, void* d_ws, size_t ws_size,
                              hipStream_t stream) {
  const float* q  = (const float*)d_in[0];  // [64,1024,64]
  const float* k  = (const float*)d_in[1];  // [64,2048,64]
  const float* v  = (const float*)d_in[2];  // [64,2048,64]
  const float* pe = (const float*)d_in[3];  // [1,64,1024]
  float* out = (float*)d_out;               // [64,1024,64] f32
  short* peT = (short*)d_ws;
  short* Kb  = (short*)((char*)d_ws + OFF_K);
  short* Vb  = (short*)((char*)d_ws + OFF_V);
  const bool preconv = ws_size >= WS_NEED;  // constant across calls: capture-safe

  dim3 grid(MQ / 64, BHN);
  if (preconv) {
    prep_fused<<<4352, 256, 0, stream>>>(pe, k, v, peT, Kb, Vb);
    seq_attn_kernel<true><<<grid, 256, 0, stream>>>(q, k, v, peT, Kb, Vb, out);
  } else {
    prep_fused<<<256, 256, 0, stream>>>(pe, k, v, peT, Kb, Vb);
    seq_attn_kernel<false><<<grid, 256, 0, stream>>>(q, k, v, peT, Kb, Vb, out);
  }
}

// Round 9
// 164.266 us; speedup vs baseline: 1.7524x; 1.1252x over previous
//
#include <hip/hip_runtime.h>
#include <hip/hip_bf16.h>

// SeqAttention: banded relative-position attention.
// out[b,i,:] = softmax_k( (q_i . key[i+k] + q_i . pe[:,k]) / 8 ) @ value[i+k,:], k in [0,1024)
//
// R16: exact R11 structure (best no-spill base, 68.5us: 64-row blocks,
// K/V/PE reg-prefetch -> LDS, raw barriers, register softmax, P-reuses-sK)
// with ONE change: pk2() uses the HW v_cvt_pk_bf16_f32 instruction via
// inline asm when the builtin is unavailable. Per guide m240 the BUILTIN
// does not exist on gfx950, so all previous rounds compiled the ~10-op
// RNE bit-twiddle fallback — x16 per wave-tile in softmax alone
// (~150 VALU ops ~ 300 issue-cyc/wave-tile, ~25% of measured VALUBusy).
// The INSTRUCTION exists and is the guide's T12 recipe (verified m214v22).
// R15 post-mortem: PE-direct without spill = 79.6us vs 68.5 -> reverted
// (L1-hit latency exposed before the PE MFMAs; LDS staging wins).
// Spill tripwire: WRITE_SIZE must stay 16384.

typedef __attribute__((ext_vector_type(8))) short bf16x8;
typedef __attribute__((ext_vector_type(4))) short bf16x4;
typedef __attribute__((ext_vector_type(4))) float f32x4;

#define BHN   64
#define MQ    1024
#define DH    64
#define LS    1024
#define NKEY  2048
#define NTILE 17

#define SZ_PE  ((size_t)LS * DH * 2)              // 131072, swizzled bf16 [rel][d]
#define OFF_K  SZ_PE
#define SZ_K   ((size_t)BHN * NKEY * DH * 2)      // bf16, rows pre-swizzled
#define OFF_V  (OFF_K + SZ_K)
#define SZ_V   ((size_t)BHN * DH * NKEY * 2)      // bf16 V^T [bh][d][kappa-key]
#define WS_NEED (OFF_V + SZ_V)                    // ~33.7 MB

// 0.125 (1/sqrt(64)) * log2(e): folded into Q before bf16 cast
#define SCL_LOG2E 0.18033688011112042f

__device__ __forceinline__ short f2bf(float f) {
  unsigned u = __float_as_uint(f);
  u += 0x7FFFu + ((u >> 16) & 1u);                // RNE (inputs finite)
  return (short)(u >> 16);
}
__device__ __forceinline__ float bf2f(short s) {
  return __uint_as_float(((unsigned)(unsigned short)s) << 16);
}

#if defined(__has_builtin)
#if __has_builtin(__builtin_amdgcn_cvt_pk_bf16_f32)
#define HAVE_CVT_PK 1
#endif
#if __has_builtin(__builtin_amdgcn_exp2f)
#define HAVE_EXP2 1
#endif
#endif

__device__ __forceinline__ float fast_exp2(float x) {
#ifdef HAVE_EXP2
  return __builtin_amdgcn_exp2f(x);               // raw v_exp_f32 (args bounded)
#else
  return __builtin_exp2f(x);
#endif
}

// pack two f32 -> two bf16 (RNE) in one unsigned.
// gfx950 HAS v_cvt_pk_bf16_f32 but (per learn_hip m240) NO builtin for it;
// use inline asm (T12 recipe). Builtin path kept first in case it appears.
__device__ __forceinline__ unsigned pk2(float a, float b) {
#ifdef HAVE_CVT_PK
  auto r = __builtin_amdgcn_cvt_pk_bf16_f32(a, b);
  unsigned u;
  __builtin_memcpy(&u, &r, 4);
  return u;
#else
  unsigned r;
  asm("v_cvt_pk_bf16_f32 %0, %1, %2" : "=v"(r) : "v"(a), "v"(b));
  return r;
#endif
}
__device__ __forceinline__ bf16x4 mk4(unsigned a, unsigned b) {
  union { unsigned u[2]; bf16x4 v; } z;
  z.u[0] = a; z.u[1] = b;
  return z.v;
}
__device__ __forceinline__ bf16x8 mk8(unsigned a, unsigned b, unsigned c, unsigned d) {
  union { unsigned u[4]; bf16x8 v; } z;
  z.u[0] = a; z.u[1] = b; z.u[2] = c; z.u[3] = d;
  return z.v;
}

// ---- fused prep: [0,256) PE, [256,2304) K, [2304,4352) V
// PE: [1,D,L] f32 -> peT [rel][d] bf16, granule-swizzled by (rel&7)
// K : [bh*2048][64] f32 -> bf16 rows, granule-swizzled by (row&7)
// V : [bh][2048][64] f32 -> bf16 V^T [bh][64][2048], key dim kappa-permuted
//     per 64-block: kappa = (k&15)*4 + (k>>4)  (inverse k = (kap&3)*16 + (kap>>2))
__global__ __launch_bounds__(256)
void prep_fused(const float* __restrict__ pe, const float* __restrict__ K,
                const float* __restrict__ V, short* __restrict__ peT,
                short* __restrict__ Kb, short* __restrict__ Vb) {
  __shared__ short st[64 * 68];
  const int bx = blockIdx.x;
  if (bx < 256) {
    const int idx = bx * 256 + threadIdx.x;       // 65536
    const int rel = idx >> 6, d = idx & 63;
    peT[rel * 64 + (((d >> 3) ^ (rel & 7)) * 8) + (d & 7)] = f2bf(pe[d * LS + rel]);
  } else if (bx < 2304) {
    const size_t i = ((size_t)(bx - 256) * 256 + threadIdx.x) * 16;  // < 8,388,608
    const int row = (int)(i >> 6);
    const int c16 = (int)(i & 63);                // 0,16,32,48
    const float4 f0 = *(const float4*)(K + i);
    const float4 f1 = *(const float4*)(K + i + 4);
    const float4 f2 = *(const float4*)(K + i + 8);
    const float4 f3 = *(const float4*)(K + i + 12);
    const bf16x8 b0 = mk8(pk2(f0.x, f0.y), pk2(f0.z, f0.w), pk2(f1.x, f1.y), pk2(f1.z, f1.w));
    const bf16x8 b1 = mk8(pk2(f2.x, f2.y), pk2(f2.z, f2.w), pk2(f3.x, f3.y), pk2(f3.z, f3.w));
    const int s7 = row & 7;
    short* dst = Kb + (size_t)row * 64;
    *(bf16x8*)&dst[(((c16 >> 3))     ^ s7) * 8] = b0;
    *(bf16x8*)&dst[(((c16 >> 3) + 1) ^ s7) * 8] = b1;
  } else {
    const int b  = bx - 2304;                     // 0..2047
    const int bh = b >> 5, jt = b & 31;
    {  // phase 1: stage 64x64 tile [key][d], f32->bf16
      const int r = threadIdx.x >> 2, cb = (threadIdx.x & 3) * 16;
      const float* src = V + ((size_t)bh * NKEY + jt * 64 + r) * DH + cb;
#pragma unroll
      for (int c = 0; c < 16; c += 8) {
        float4 f0 = *(const float4*)(src + c);
        float4 f1 = *(const float4*)(src + c + 4);
        *(bf16x8*)&st[r * 68 + cb + c] =
            mk8(pk2(f0.x, f0.y), pk2(f0.z, f0.w), pk2(f1.x, f1.y), pk2(f1.z, f1.w));
      }
    }
    __syncthreads();
    {  // phase 2: transpose + kappa-permute, contiguous b128 writes
      const int d = threadIdx.x >> 2, kapb = (threadIdx.x & 3) * 16;
      __attribute__((aligned(16))) short tmp[16];
#pragma unroll
      for (int j = 0; j < 16; ++j) {
        const int kap = kapb + j;
        const int k   = (kap & 3) * 16 + (kap >> 2);
        tmp[j] = st[k * 68 + d];
      }
      short* dst = Vb + ((size_t)bh * DH + d) * NKEY + jt * 64 + kapb;
      *(bf16x8*)dst       = *(bf16x8*)&tmp[0];
      *(bf16x8*)(dst + 8) = *(bf16x8*)&tmp[8];
    }
  }
}

template <bool PRECONV>
__global__ __launch_bounds__(256, 4)
void seq_attn_kernel(const float* __restrict__ Qf, const float* __restrict__ Kf,
                     const float* __restrict__ Vf, const short* __restrict__ peT,
                     const short* __restrict__ Kb, const short* __restrict__ Vb,
                     float* __restrict__ Out) {
  // stride-64 + granule-XOR layouts: slot = (g ^ (row&7)), g = 16B granule.
  __shared__ short sK[64 * 64];        // [key][d-gran swz]; P after bar3    8KB
  __shared__ short sPE[2 * 64 * 64];   // 2-slot circular PE blocks          16KB
  __shared__ short sV[64 * 64];        // [d][kappa-granules swizzled]       8KB
  // total 32KB -> 4 blocks/CU (grid-capped at 4/CU)

  const int tid  = threadIdx.x;
  const int w    = tid >> 6;
  const int lane = tid & 63;
  const int li   = lane & 15;
  const int quad = lane >> 4;
  // XCD-aware swizzle: 8 consecutive bh per XCD (Kb+Vb working set = 4MB = L2)
  const int linear = blockIdx.y * 16 + blockIdx.x;
  const int slot   = linear >> 3;
  const int bh     = (linear & 7) * 8 + (slot >> 4);
  const int i0     = (slot & 15) * 64;
  const int rbase  = w * 16 + quad * 4;

  // ---- Q A-fragments, pre-scaled by 0.125*log2(e) so exp2 args are bare adds
  bf16x8 aq[2];
  {
    const float* qp = Qf + (size_t)((bh * MQ + i0 + w * 16 + li) * DH) + quad * 8;
#pragma unroll
    for (int ks = 0; ks < 2; ++ks) {
      float4 f0 = *(const float4*)(qp + ks * 32);
      float4 f1 = *(const float4*)(qp + ks * 32 + 4);
      f0.x *= SCL_LOG2E; f0.y *= SCL_LOG2E; f0.z *= SCL_LOG2E; f0.w *= SCL_LOG2E;
      f1.x *= SCL_LOG2E; f1.y *= SCL_LOG2E; f1.z *= SCL_LOG2E; f1.w *= SCL_LOG2E;
      aq[ks] = mk8(pk2(f0.x, f0.y), pk2(f0.z, f0.w), pk2(f1.x, f1.y), pk2(f1.z, f1.w));
    }
  }

  float l_i[4] = {0.f, 0.f, 0.f, 0.f};
  f32x4 acco[4];
#pragma unroll
  for (int nt = 0; nt < 4; ++nt) acco[nt] = (f32x4){0.f, 0.f, 0.f, 0.f};

  f32x4 curPw[4];   // P over rel cols (4t-w+m)*16.., m=0..3 (per-wave window)
  f32x4 prevw3 = (f32x4){0.f, 0.f, 0.f, 0.f};

  // ---- reg-staging prefetch state (tile t+1 loads fly across compute of t).
  // LDS dst slots linear (thread tid -> 16B slots tid, tid+256); the V
  // granule-XOR is applied on the SOURCE address (t-invariant per thread).
  bf16x8 pfK0, pfK1, pfP0, pfP1, pfV0, pfV1;
  const short *pK, *pP, *pV0, *pV1;
  if constexpr (PRECONV) {
    pK = Kb + ((size_t)bh * NKEY + i0) * DH + tid * 8 + 1024;   // +-1024sh imm
    pP = peT + tid * 8 + 1024;
    const int d0 = tid >> 3;
    const int g0 = (tid & 7) ^ (d0 & 7);          // same XOR for slot tid+256
    pV0 = Vb + ((size_t)bh * DH + d0) * NKEY + i0 + g0 * 8;
    pV1 = pV0 + (size_t)32 * NKEY;
    pfK0 = *(const bf16x8*)(pK - 1024);
    pfK1 = *(const bf16x8*)(pK + 1024);
    pfP0 = *(const bf16x8*)(pP - 1024);
    pfP1 = *(const bf16x8*)(pP + 1024);
    pfV0 = *(const bf16x8*)(pV0);
    pfV1 = *(const bf16x8*)(pV1);
    pK += 4096; pP += 4096; pV0 += 64; pV1 += 64;
  }

  for (int t = 0; t < NTILE; ++t) {
    if constexpr (PRECONV) {
      // Raw entry barrier: previous tile's PV sK/sV reads retired (lgkm 0
      // per wave + barrier); pf-reg vmcnt waits happen at the ds_writes.
      asm volatile("s_waitcnt lgkmcnt(0)" ::: "memory");
      __builtin_amdgcn_sched_barrier(0);
      __builtin_amdgcn_s_barrier();
      __builtin_amdgcn_sched_barrier(0);
      // ---- ds_write staged tile t (linear, stride-16B, conflict-free)
      *(bf16x8*)&sK[tid * 8]        = pfK0;
      *(bf16x8*)&sK[tid * 8 + 2048] = pfK1;
      if (t < NTILE - 1) {
        short* ped = sPE + (size_t)(t & 1) * 4096;
        *(bf16x8*)&ped[tid * 8]        = pfP0;
        *(bf16x8*)&ped[tid * 8 + 2048] = pfP1;
      }
      *(bf16x8*)&sV[tid * 8]        = pfV0;
      *(bf16x8*)&sV[tid * 8 + 2048] = pfV1;
      // ---- issue prefetch for tile t+1; flies across the raw barriers and
      // both compute phases (waited at next tile's ds_writes)
      if (t + 1 < NTILE) {
        pfK0 = *(const bf16x8*)(pK - 1024);
        pfK1 = *(const bf16x8*)(pK + 1024);
        pfV0 = *(const bf16x8*)(pV0);
        pfV1 = *(const bf16x8*)(pV1);
        pK += 4096; pV0 += 64; pV1 += 64;
        if (t + 1 < NTILE - 1) {
          pfP0 = *(const bf16x8*)(pP - 1024);
          pfP1 = *(const bf16x8*)(pP + 1024);
          pP += 4096;
        }
      }
      // RAW barrier: wait only on LDS writes, NOT vmem — prefetch flies.
      asm volatile("s_waitcnt lgkmcnt(0)" ::: "memory");
      __builtin_amdgcn_sched_barrier(0);
      __builtin_amdgcn_s_barrier();
      __builtin_amdgcn_sched_barrier(0);
    } else {
      // ---- fallback: stage with in-kernel f32->bf16 conversion
      __syncthreads();
      const int j0 = i0 + t * 64;
      {
        const int srow = tid >> 2, l0 = tid & 3, sdb = l0 * 16;
        const float* src = Kf + (size_t)(bh * NKEY + j0 + srow) * DH + sdb;
        const float4 a0 = *(const float4*)(src + 0);
        const float4 a1 = *(const float4*)(src + 4);
        const float4 a2 = *(const float4*)(src + 8);
        const float4 a3 = *(const float4*)(src + 12);
        const bf16x8 b0 = mk8(pk2(a0.x, a0.y), pk2(a0.z, a0.w), pk2(a1.x, a1.y), pk2(a1.z, a1.w));
        const bf16x8 b1 = mk8(pk2(a2.x, a2.y), pk2(a2.z, a2.w), pk2(a3.x, a3.y), pk2(a3.z, a3.w));
        const int s7 = srow & 7;
        *(bf16x8*)&sK[srow * 64 + (((2 * l0)     ^ s7) * 8)] = b0;
        *(bf16x8*)&sK[srow * 64 + (((2 * l0 + 1) ^ s7) * 8)] = b1;
      }
      {
        const int vdb = (tid & 15) * 4, vkb = (tid >> 4) * 4;
        const float* src = Vf + (size_t)(bh * NKEY + j0 + vkb) * DH + vdb;
#pragma unroll
        for (int m = 0; m < 4; ++m) {             // key vkb+m
          const float4 rr = *(const float4*)(src + m * DH);
          const int k   = vkb + m;
          const int kap = (k & 15) * 4 + (k >> 4);
#pragma unroll
          for (int jj = 0; jj < 4; ++jj) {
            const int d = vdb + jj;
            const float fv = (jj == 0) ? rr.x : (jj == 1) ? rr.y : (jj == 2) ? rr.z : rr.w;
            sV[d * 64 + (((kap >> 3) ^ (d & 7)) * 8) + (kap & 7)] = f2bf(fv);
          }
        }
      }
      if (t < NTILE - 1) {
        const short* src = peT + (size_t)t * 64 * 64;   // already swizzled
        short* db = sPE + (size_t)(t & 1) * 4096;
        *(bf16x8*)&db[tid * 16]     = *(const bf16x8*)(src + tid * 16);
        *(bf16x8*)&db[tid * 16 + 8] = *(const bf16x8*)(src + tid * 16 + 8);
      }
      __syncthreads();
    }

    // ---- curPw[m] = Q @ PE over rel col (4t-w+m)*16..+15 (per-wave window).
    // Out-of-range cols read defined-but-stale LDS; killed by the band mask.
    __builtin_amdgcn_s_setprio(1);
#pragma unroll
    for (int m = 0; m < 4; ++m) {
      const int colIdx = 4 * t - w + m;
      const int base = ((colIdx >> 2) & 1) * 4096 + ((colIdx & 3) * 16 + li) * 64;
      f32x4 c = (f32x4){0.f, 0.f, 0.f, 0.f};
#pragma unroll
      for (int ks = 0; ks < 2; ++ks) {
        const int gs = (((ks * 4 + quad) ^ (li & 7)) * 8);
        const bf16x8 b = *(bf16x8*)&sPE[base + gs];
        c = __builtin_amdgcn_mfma_f32_16x16x32_bf16(aq[ks], b, c, 0, 0, 0);
      }
      curPw[m] = c;
    }

    // ---- S = Q @ K^T (Q pre-scaled, so cs is already in log2-units)
    f32x4 cs[4];
#pragma unroll
    for (int nt = 0; nt < 4; ++nt) {
      f32x4 c = (f32x4){0.f, 0.f, 0.f, 0.f};
#pragma unroll
      for (int ks = 0; ks < 2; ++ks) {
        const int gs = (((ks * 4 + quad) ^ (li & 7)) * 8);
        const bf16x8 b = *(bf16x8*)&sK[(nt * 16 + li) * 64 + gs];
        c = __builtin_amdgcn_mfma_f32_16x16x32_bf16(aq[ks], b, c, 0, 0, 0);
      }
      cs[nt] = c;
    }
    __builtin_amdgcn_s_setprio(0);

    // ---- register-phase softmax: diagonal gather (3 packed shuffles per r)
    // + no-max exp2; produces pkv[4] (8 VGPRs). cs/cur die HERE — only pkv
    // crosses bar3 (small live set: R10/R13 spill lesson).
    bf16x4 pkv[4];
#pragma unroll
    for (int r = 0; r < 4; ++r) {
      const int e       = li - quad * 4 - r;          // in [-15, 15]
      const bool ge     = (e >= 0);
      const int srcLane = quad * 16 + (e & 15);
      const float shm = __shfl(prevw3[r], srcLane);
      const unsigned pk01 = pk2(curPw[0][r], curPw[1][r]);
      const unsigned pk23 = pk2(curPw[2][r], curPw[3][r]);
      const unsigned s01 = (unsigned)__shfl((int)pk01, srcLane);
      const unsigned s23 = (unsigned)__shfl((int)pk23, srcLane);
      const float sh0 = bf2f((short)(s01 & 0xffffu));
      const float sh1 = bf2f((short)(s01 >> 16));
      const float sh2 = bf2f((short)(s23 & 0xffffu));
      const float sh3 = bf2f((short)(s23 >> 16));
      const float pos0 = ge ? sh0 : shm;
      const float pos1 = ge ? sh1 : sh0;
      const float pos2 = ge ? sh2 : sh1;
      const float pos3 = ge ? sh3 : sh2;
      float p0 = fast_exp2(cs[0][r] + pos0);
      float p1 = fast_exp2(cs[1][r] + pos1);
      float p2 = fast_exp2(cs[2][r] + pos2);
      float p3 = fast_exp2(cs[3][r] + pos3);
      if (t == 0) {                 // valid iff dl>=0: nt>w || (nt==w && ge)
        p0 = (0 > w || (0 == w && ge)) ? p0 : 0.f;
        p1 = (1 > w || (1 == w && ge)) ? p1 : 0.f;
        p2 = (2 > w || (2 == w && ge)) ? p2 : 0.f;
        p3 = (3 > w || (3 == w && ge)) ? p3 : 0.f;
      } else if (t == NTILE - 1) {  // valid iff dl<0: nt<w || (nt==w && !ge)
        p0 = (0 < w || (0 == w && !ge)) ? p0 : 0.f;
        p1 = (1 < w || (1 == w && !ge)) ? p1 : 0.f;
        p2 = (2 < w || (2 == w && !ge)) ? p2 : 0.f;
        p3 = (3 < w || (3 == w && !ge)) ? p3 : 0.f;
      }
      l_i[r] += (p0 + p1) + (p2 + p3);
      pkv[r] = mk4(pk2(p0, p1), pk2(p2, p3));
    }
    prevw3 = curPw[3];

    // ---- bar3: all waves' QK^T sK reads + shuffles retired -> sK becomes
    // the P buffer (stripes wave-private: wave w rows w*16..w*16+15).
    asm volatile("s_waitcnt lgkmcnt(0)" ::: "memory");
    __builtin_amdgcn_sched_barrier(0);
    __builtin_amdgcn_s_barrier();
    __builtin_amdgcn_sched_barrier(0);

    // kappa-order store: lane li's keys nt*16+li -> kappa = 4*li + nt,
    // contiguous => one b64. Granule (li>>1) ^ (rowA&7), offset (li&1)*4.
#pragma unroll
    for (int r = 0; r < 4; ++r) {
      const int rowA = rbase + r;
      *(bf16x4*)&sK[rowA * 64 + (((li >> 1) ^ (rowA & 7)) * 8) + (li & 1) * 4] = pkv[r];
    }

    // ---- O += P @ V  (kappa-ordered contraction on both operands)
    __builtin_amdgcn_s_setprio(1);
#pragma unroll
    for (int ks = 0; ks < 2; ++ks) {
      const int rowA = w * 16 + li;
      const bf16x8 ap =
          *(bf16x8*)&sK[rowA * 64 + (((ks * 4 + quad) ^ (rowA & 7)) * 8)];
#pragma unroll
      for (int nt = 0; nt < 4; ++nt) {
        const int d  = nt * 16 + li;
        const int gs = (((ks * 4 + quad) ^ (d & 7)) * 8);
        const bf16x8 bv = *(bf16x8*)&sV[d * 64 + gs];
        acco[nt] = __builtin_amdgcn_mfma_f32_16x16x32_bf16(ap, bv, acco[nt], 0, 0, 0);
      }
    }
    __builtin_amdgcn_s_setprio(0);
  }

  // ---- epilogue: reduce l across the 16 lanes holding each row, out = O / l
#pragma unroll
  for (int r = 0; r < 4; ++r) {
    float l = l_i[r];
    l += __shfl_xor(l, 1);
    l += __shfl_xor(l, 2);
    l += __shfl_xor(l, 4);
    l += __shfl_xor(l, 8);
    const float inv = 1.0f / l;
#pragma unroll
    for (int nt = 0; nt < 4; ++nt) {
      Out[(size_t)(bh * MQ + i0 + rbase + r) * DH + nt * 16 + li] = acco[nt][r] * inv;
    }
  }
}

extern "C" void kernel_launch(void* const* d_in, const int* in_sizes, int n_in,
                              void* d_out, int out_size, void* d_ws, size_t ws_size,
                              hipStream_t stream) {
  const float* q  = (const float*)d_in[0];  // [64,1024,64]
  const float* k  = (const float*)d_in[1];  // [64,2048,64]
  const float* v  = (const float*)d_in[2];  // [64,2048,64]
  const float* pe = (const float*)d_in[3];  // [1,64,1024]
  float* out = (float*)d_out;               // [64,1024,64] f32
  short* peT = (short*)d_ws;
  short* Kb  = (short*)((char*)d_ws + OFF_K);
  short* Vb  = (short*)((char*)d_ws + OFF_V);
  const bool preconv = ws_size >= WS_NEED;  // constant across calls: capture-safe

  dim3 grid(MQ / 64, BHN);
  if (preconv) {
    prep_fused<<<4352, 256, 0, stream>>>(pe, k, v, peT, Kb, Vb);
    seq_attn_kernel<true><<<grid, 256, 0, stream>>>(q, k, v, peT, Kb, Vb, out);
  } else {
    prep_fused<<<256, 256, 0, stream>>>(pe, k, v, peT, Kb, Vb);
    seq_attn_kernel<false><<<grid, 256, 0, stream>>>(q, k, v, peT, Kb, Vb, out);
  }
}